// Round 1
// baseline (580.757 us; speedup 1.0000x reference)
//
#include <hip/hip_runtime.h>

// out[b,i,j] = W[words[b,i], words[b,j]]  (+ root[words[b,i]] when i==j)
// B=8, N=2048, V=10000. Output fp32, 128 MiB.
//
// R3: persistent blocks + double-buffered LDS staging, software-pipelined.
// R2 (580us) was phase-serialized: per-row block did stage -> vmcnt(0) drain
// (all waves idle) -> tiny gather -> exit -> relaunch; HBM idle between
// bursts (1.36 TB/s eff. vs 6.5 TB/s the fill kernel achieves on this chip).
// Now: 1024 persistent blocks (2/CU, 80KB LDS), each owns 16 rows. DMA for
// row k+1 is in flight into buf[!cur] while row k is gathered from buf[cur].
// One __syncthreads per row: its per-wave vmcnt(0) is precisely the
// "my DMA landed" wait; next-row DMA is issued after it, so it stays in
// flight across the gather. wi/root prefetched 2 rows ahead (kills the
// scalar address->issue chain); wj int4 column indices are block-constant
// and loaded once.

#define VOCAB  10000
#define BATCH  8
#define SEQ    2048
#define TPB    512
#define RPB    16                    // rows per persistent block
#define NROWS  (BATCH * SEQ)         // 16384
#define NBLK   (NROWS / RPB)         // 1024 = 2 blocks/CU on 256 CUs
#define NCHUNK (VOCAB / 4)           // 2500 float4 chunks per row

__device__ __forceinline__ void stage_row(const float* __restrict__ src,
                                          float* dst /* LDS */)
{
    // 2500 float4 chunks; dest = uniform base + lane*16 as LDS-DMA requires.
    #pragma unroll
    for (int it = 0; it < 5; ++it) {
        const int idx = it * TPB + (int)threadIdx.x;   // float4 index
        if (idx < NCHUNK) {
            __builtin_amdgcn_global_load_lds(
                (const __attribute__((address_space(1))) void*)(src + idx * 4),
                (__attribute__((address_space(3))) void*)(dst + idx * 4),
                16, 0, 0);
        }
    }
}

__global__ __launch_bounds__(TPB) void gather2d_pipe_kernel(
    const int*   __restrict__ words,
    const float* __restrict__ W,
    const float* __restrict__ root,
    float*       __restrict__ out)
{
    __shared__ float buf[2][VOCAB];     // 80000 B -> 2 blocks/CU (160KB LDS)

    const int r0 = blockIdx.x * RPB;    // first global output row
    const int b  = r0 / SEQ;            // chunk never crosses a batch (16|2048)
    const int i0 = r0 % SEQ;
    const int* __restrict__ wrow = words + b * SEQ;
    float* __restrict__ obase = out + ((size_t)b * SEQ + i0) * SEQ;

    // Block-constant per-thread column indices: load once, keep in VGPRs.
    const int  j  = (int)threadIdx.x * 4;       // SEQ == TPB*4
    const int4 wj = *(const int4*)(wrow + j);

    // Scalar software pipeline (all block-uniform -> SGPRs):
    //   wi_cur = words row for iter k, wi_nxt = k+1, rs_cur = root[wi_cur].
    int   wi_cur = wrow[i0];
    int   wi_nxt = wrow[i0 + 1];
    float rs_cur = root[wi_cur];

    // Prologue: stage row 0 into buf[0].
    stage_row(W + (size_t)wi_cur * VOCAB, buf[0]);

    #pragma unroll
    for (int k = 0; k < RPB; ++k) {
        // Per-wave vmcnt(0): my DMA chunks for buf[k&1] landed.
        // Barrier: everyone's landed, and everyone is done reading buf[!cur]
        // from iter k-1 -> safe to overwrite it below.
        __syncthreads();

        // Issue next row's DMA immediately: in flight during this gather.
        if (k + 1 < RPB)
            stage_row(W + (size_t)wi_nxt * VOCAB, buf[(k + 1) & 1]);

        // Prefetch scalars two rows ahead (full iteration of latency slack).
        const int   wi_fut = wrow[i0 + ((k + 2 < RPB) ? (k + 2) : 0)];
        const float rs_nxt = root[wi_nxt];

        // Gather row k from LDS; each thread one float4 of output.
        const float* __restrict__ rp = buf[k & 1];
        float4 v;
        v.x = rp[wj.x];
        v.y = rp[wj.y];
        v.z = rp[wj.z];
        v.w = rp[wj.w];
        const unsigned d = (unsigned)((i0 + k) - j);
        if (d < 4u) ((float*)&v)[d] += rs_cur;
        *(float4*)(obase + (size_t)k * SEQ + j) = v;

        // Rotate the scalar pipeline.
        wi_cur = wi_nxt;
        rs_cur = rs_nxt;
        wi_nxt = wi_fut;
    }
}

extern "C" void kernel_launch(void* const* d_in, const int* in_sizes, int n_in,
                              void* d_out, int out_size, void* d_ws, size_t ws_size,
                              hipStream_t stream)
{
    const int*   words = (const int*)d_in[0];
    const float* W     = (const float*)d_in[1];
    const float* root  = (const float*)d_in[2];
    float*       out   = (float*)d_out;

    dim3 grid(NBLK);
    gather2d_pipe_kernel<<<grid, TPB, 0, stream>>>(words, W, root, out);
}